// Round 17
// baseline (9000.339 us; speedup 1.0000x reference)
//
#include <hip/hip_runtime.h>
#include <math.h>

// ---------------------------------------------------------------------------
// RPN forward — round 17: target = numpy-translated reference (einsum conv):
//  - conv: k = ci*9+tap (ci OUTER, tap inner), sequential chain, SEPARATE
//    mul+add (no FMA) — np.einsum(optimize=False) baseline-build semantics
//  - heads: sequential K=256 chain, separate mul+add
//  - decode: strict f32 separate ops (numpy elementwise), CR exp
//  - selection/NMS: exact sorts, stable ties, f32 IoU in reference op order
// ---------------------------------------------------------------------------

#define NC_TOT 246840
typedef unsigned long long u64;
typedef unsigned int u32;
typedef unsigned char u8;

struct Anc48 { float v[48]; };   // 4 levels x 3 anchors x (x1,y1,x2,y2)

__device__ __forceinline__ u32 sortable32(float f) {
  u32 u = __float_as_uint(f);
  return (u & 0x80000000u) ? ~u : (u | 0x80000000u);
}
__device__ __forceinline__ int lvl_base_of(int lvl) {
  return (lvl == 0) ? 0 : (lvl == 1) ? 185856 : (lvl == 2) ? 232320 : 243936;
}
__device__ __forceinline__ int lvl_N_of(int lvl) {
  return (lvl == 0) ? 185856 : (lvl == 1) ? 46464 : (lvl == 2) ? 11616 : 2904;
}

// ---------------------------------------------------------------------------
// weight transpose: wt[(ci*9+tap)*256 + co] = wconv[co][ci][tap]
// ---------------------------------------------------------------------------
__global__ __launch_bounds__(256)
void wtr_k(const float* __restrict__ wconv, float* __restrict__ wt) {
  int g = blockIdx.x * 256 + threadIdx.x;
  if (g >= 589824) return;
  wt[g] = wconv[(size_t)(g & 255) * 2304 + (g >> 8)];
}

// ---------------------------------------------------------------------------
// conv+heads+decode, f32, NO fused multiply-add anywhere (numpy semantics).
// Conv K-loop: ci 0..255 outer, tap 0..8 inner, sequential chain.
// Block=256, tile 8(w)x4(h) pixels; thread=(cog 0..31, slot 0..7).
// ---------------------------------------------------------------------------
template<int H, int W, int STRIDE>
__global__ __launch_bounds__(256)
void conv_f32(const float* __restrict__ x, const float* __restrict__ wt,
              const float* __restrict__ bconv, const float* __restrict__ wobj,
              const float* __restrict__ bobj, const float* __restrict__ wdel,
              const float* __restrict__ bdel,
              float* __restrict__ logitsB, u8* __restrict__ validB,
              float* __restrict__ boxesB, int lvl, Anc48 anc, int tiles_x)
{
#pragma clang fp contract(off)
  __shared__ __align__(16) char smem[61440];
  float* xs = (float*)smem;                 // [256][6][10]
  const int tid = threadIdx.x;
  const int img = blockIdx.y;
  const int ty = blockIdx.x / tiles_x, tx = blockIdx.x - ty * tiles_x;
  const int y0 = ty * 4, x0 = tx * 8;
  const int base = lvl_base_of(lvl);
  const float* xin = x + (size_t)img * 256 * H * W;

  for (int idx = tid; idx < 256 * 60; idx += 256) {
    int ci = idx / 60; int rem = idx - ci * 60;
    int r = rem / 10; int c = rem - r * 10;
    int gy = y0 - 1 + r, gx = x0 - 1 + c;
    float v = 0.f;
    if (gy >= 0 && gy < H && gx >= 0 && gx < W)
      v = xin[(size_t)ci * H * W + (size_t)gy * W + gx];
    xs[idx] = v;
  }
  __syncthreads();

  const int cog = tid >> 3, slot = tid & 7;
  const int row = slot >> 1, half = slot & 1;
  float acc[8][4];
#pragma unroll
  for (int c = 0; c < 8; ++c)
#pragma unroll
    for (int j = 0; j < 4; ++j) acc[c][j] = 0.f;

  for (int ci = 0; ci < 256; ++ci) {
    // 3 rows x 6 cols for this ci (8B-aligned float2 reads)
    float xr[3][6];
#pragma unroll
    for (int dr = 0; dr < 3; ++dr) {
      const float* rp = &xs[ci * 60 + (row + dr) * 10 + half * 4];
      float2 av = *(const float2*)(rp);
      float2 bv = *(const float2*)(rp + 2);
      float2 cv = *(const float2*)(rp + 4);
      xr[dr][0] = av.x; xr[dr][1] = av.y; xr[dr][2] = bv.x;
      xr[dr][3] = bv.y; xr[dr][4] = cv.x; xr[dr][5] = cv.y;
    }
#pragma unroll
    for (int tap = 0; tap < 9; ++tap) {
      const int ky = tap / 3, kx = tap - ky * 3;
      const float4* wp = (const float4*)(wt + (((size_t)(ci * 9 + tap)) << 8)
                                         + (cog << 3));
      float4 wA = wp[0], wB = wp[1];
      float wv[8] = {wA.x, wA.y, wA.z, wA.w, wB.x, wB.y, wB.z, wB.w};
#pragma unroll
      for (int c = 0; c < 8; ++c) {
        // separate mul and add, each rounded (no contraction)
        acc[c][0] = acc[c][0] + (xr[ky][kx + 0] * wv[c]);
        acc[c][1] = acc[c][1] + (xr[ky][kx + 1] * wv[c]);
        acc[c][2] = acc[c][2] + (xr[ky][kx + 2] * wv[c]);
        acc[c][3] = acc[c][3] + (xr[ky][kx + 3] * wv[c]);
      }
    }
  }
  __syncthreads();                 // all xs reads done

  // bias + relu -> t in LDS [256 co][32 px]  (separate f32 ops)
  float* tl = (float*)smem;
  {
#pragma unroll
    for (int c = 0; c < 8; ++c) {
      float bv = bconv[cog * 8 + c];
#pragma unroll
      for (int j = 0; j < 4; ++j) {
        float v = acc[c][j] + bv;
        v = fmaxf(v, 0.f);
        tl[(cog * 8 + c) * 32 + row * 8 + half * 4 + j] = v;
      }
    }
  }
  __syncthreads();

  // heads: per pixel, 15 dots, sequential separate mul+add over co 0..255
  float* hd = (float*)(smem + 32768);   // [15][32]
  if (tid < 32) {
    int p = tid;
    for (int ch = 0; ch < 15; ++ch) {
      const float* wh = (ch < 3) ? (wobj + (size_t)ch * 256)
                                 : (wdel + (size_t)(ch - 3) * 256);
      float s = 0.f;
      for (int co = 0; co < 256; ++co) s = s + (tl[co * 32 + p] * wh[co]);
      hd[ch * 32 + p] = s;
    }
  }
  __syncthreads();

  // decode: strict f32 separate ops everywhere (numpy elementwise), CR exp
  if (tid < 96) {
    int p = tid / 3, a = tid - p * 3;
    int X = x0 + (p & 7), Y = y0 + (p >> 3);
    if (X < W && Y < H) {
      float sx = (float)(X * STRIDE), sy = (float)(Y * STRIDE);
      const float* av = &anc.v[lvl * 12 + a * 4];
      size_t cbase = (size_t)img * NC_TOT + (size_t)base + (size_t)(Y * W + X) * 3;
      float lg = hd[a * 32 + p] + bobj[a];
      float dx = hd[(3 + a * 4 + 0) * 32 + p] + bdel[a * 4 + 0];
      float dy = hd[(3 + a * 4 + 1) * 32 + p] + bdel[a * 4 + 1];
      float dw = hd[(3 + a * 4 + 2) * 32 + p] + bdel[a * 4 + 2];
      float dh = hd[(3 + a * 4 + 3) * 32 + p] + bdel[a * 4 + 3];
      float x1a = sx + av[0], y1a = sy + av[1];
      float x2a = sx + av[2], y2a = sy + av[3];
      float wa = x2a - x1a, ha = y2a - y1a;
      float cxa = x1a + 0.5f * wa, cya = y1a + 0.5f * ha;
      float dwc = fminf(dw, (float)4.135166556742356);
      float dhc = fminf(dh, (float)4.135166556742356);
      float pcx = (dx * wa) + cxa, pcy = (dy * ha) + cya;
      float ew = (float)exp((double)dwc);   // correctly-rounded f32 exp
      float eh = (float)exp((double)dhc);
      float pw = ew * wa, ph = eh * ha;
      float bx1 = pcx - (0.5f * pw), by1 = pcy - (0.5f * ph);
      float bx2 = pcx + (0.5f * pw), by2 = pcy + (0.5f * ph);
      bx1 = fminf(fmaxf(bx1, 0.f), 1408.f);
      bx2 = fminf(fmaxf(bx2, 0.f), 1408.f);
      by1 = fminf(fmaxf(by1, 0.f), 704.f);
      by2 = fminf(fmaxf(by2, 0.f), 704.f);
      bool vld = (bx2 - bx1 > 0.f) && (by2 - by1 > 0.f);
      logitsB[cbase + a] = lg;
      validB[cbase + a] = vld ? 1 : 0;
      *(float4*)(boxesB + (cbase + a) * 4) = make_float4(bx1, by1, bx2, by2);
    }
  }
}

// ---------------------------------------------------------------------------
// selection: exact per-(img,lvl) sort on u64 key = ~sortable(logit)<<32 | jrel
// ---------------------------------------------------------------------------
__global__ __launch_bounds__(256)
void fill_sel(const float* __restrict__ logits, u64* __restrict__ K) {
  int g = blockIdx.x * 256 + threadIdx.x;
  if (g >= 8 * 262144) return;
  int seg = g >> 18; int e = g & 0x3FFFF;
  int img = seg >> 2, lvl = seg & 3;
  if (e < lvl_N_of(lvl)) {
    float lg = logits[(size_t)img * NC_TOT + lvl_base_of(lvl) + e];
    K[g] = ((u64)(~sortable32(lg)) << 32) | (u32)e;
  } else K[g] = ~0ull;
}

// segment-local bitonic pass (u64 keys, payload embedded)
__global__ __launch_bounds__(256)
void bpass1(u64* __restrict__ K, int k, int j, int total, int segmask) {
  int i = blockIdx.x * 256 + threadIdx.x;
  if (i >= total) return;
  int ij = i ^ j;
  if (ij <= i) return;
  bool up = (((i & segmask) & k) == 0);
  u64 a = K[i], b = K[ij];
  if ((a > b) == up) { K[i] = b; K[ij] = a; }
}

// ---------------------------------------------------------------------------
// NMS keys: key = ~sortable(score)<<32 | concat_pos   (stable argsort match)
// ---------------------------------------------------------------------------
__global__ __launch_bounds__(256)
void fill_nms(const u64* __restrict__ Ksel, const float* __restrict__ logits,
              const u8* __restrict__ validB, u64* __restrict__ K,
              u32* __restrict__ sel_cand) {
  int g = blockIdx.x * 256 + threadIdx.x;
  if (g >= 2 * 8192) return;
  int img = g >> 13; int pos = g & 8191;
  if (pos < 8000) {
    int lvl = pos / 2000, rank = pos - lvl * 2000;
    int seg = img * 4 + lvl;
    int jrel = (int)(u32)Ksel[((size_t)seg << 18) + rank];
    int cand = lvl_base_of(lvl) + jrel;
    sel_cand[img * 8000 + pos] = (u32)cand;
    size_t ci = (size_t)img * NC_TOT + cand;
    float sc = validB[ci] ? logits[ci] : -1e9f;
    K[g] = ((u64)(~sortable32(sc)) << 32) | (u32)pos;
  } else K[g] = ~0ull;
}

__global__ __launch_bounds__(512)
void sortnms_k(u64* __restrict__ K) {
  __shared__ u64 key[8192];
  const int tid = threadIdx.x; const int img = blockIdx.x;
  for (int i = tid; i < 8192; i += 512) key[i] = K[img * 8192 + i];
  __syncthreads();
  for (int kk = 2; kk <= 8192; kk <<= 1) {
    for (int j = kk >> 1; j > 0; j >>= 1) {
      for (int i = tid; i < 8192; i += 512) {
        int ij = i ^ j;
        if (ij > i) {
          bool up = ((i & kk) == 0);
          u64 a = key[i], b = key[ij];
          if ((a > b) == up) { key[i] = b; key[ij] = a; }
        }
      }
      __syncthreads();
    }
  }
  for (int i = tid; i < 8192; i += 512) K[img * 8192 + i] = key[i];
}

// ---------------------------------------------------------------------------
// kept-list greedy NMS, f32 IoU with reference op order on OFFSET boxes
// (strict mul/add, no contraction)
// ---------------------------------------------------------------------------
__global__ __launch_bounds__(64)
void nms_f32_k(const u64* __restrict__ Knms, const u32* __restrict__ sel_cand,
               const float* __restrict__ logits, const u8* __restrict__ validB,
               const float* __restrict__ boxes, float* __restrict__ out) {
#pragma clang fp contract(off)
  __shared__ float kb[1000][4];
  __shared__ float kA[1000];
  const int img = blockIdx.x; const int lane = threadIdx.x;
  int nk = 0;
  for (int i = 0; i < 8000 && nk < 1000; ++i) {
    u64 key = Knms[img * 8192 + i];
    int pos = (int)(u32)key;
    int cand = (int)sel_cand[img * 8000 + pos];
    size_t ci = (size_t)img * NC_TOT + cand;
    if (!validB[ci]) continue;
    const float4 b = *(const float4*)(boxes + ci * 4);
    int lvl = pos / 2000;
    float off = (float)lvl * 4096.0f;
    float x1 = b.x + off, y1 = b.y + off, x2 = b.z + off, y2 = b.w + off;
    float areaC = (x2 - x1) * (y2 - y1);
    bool sup = false;
    for (int bse = 0; bse < nk; bse += 64) {
      int j = bse + lane;
      bool s = false;
      if (j < nk) {
        float kx1 = kb[j][0], ky1 = kb[j][1], kx2 = kb[j][2], ky2 = kb[j][3];
        float ltx = fmaxf(kx1, x1), lty = fmaxf(ky1, y1);
        float rbx = fminf(kx2, x2), rby = fminf(ky2, y2);
        float w = fmaxf(rbx - ltx, 0.f), h = fmaxf(rby - lty, 0.f);
        float inter = w * h;
        float uni = (kA[j] + areaC) - inter;
        s = (uni > 0.f) && ((inter / uni) > 0.7f);
      }
      if (__ballot(s)) { sup = true; break; }
    }
    if (!sup) {
      if (lane == 0) {
        kb[nk][0] = x1; kb[nk][1] = y1; kb[nk][2] = x2; kb[nk][3] = y2;
        kA[nk] = areaC;
        float* o = out + ((size_t)img * 1000 + nk) * 5;
        o[0] = b.x; o[1] = b.y; o[2] = b.z; o[3] = b.w;
        o[4] = logits[ci];
      }
      ++nk;
      __syncthreads();
    }
  }
  __syncthreads();
  for (int r = lane; r < 1000; r += 64)
    if (r >= nk) {
      float* o = out + ((size_t)img * 1000 + r) * 5;
      o[0] = 0.f; o[1] = 0.f; o[2] = 0.f; o[3] = 0.f; o[4] = -1e9f;
    }
}

// ---------------------------------------------------------------------------
static void make_anc48(Anc48& a) {
  const double sizes[4] = {32.0, 64.0, 128.0, 256.0};
  const double ratios[3] = {0.5, 1.0, 2.0};
  for (int L = 0; L < 4; ++L)
    for (int i = 0; i < 3; ++i) {
      double w = sizes[L] * sqrt(1.0 / ratios[i]);
      double h = sizes[L] * sqrt(ratios[i]);
      a.v[L * 12 + i * 4 + 0] = (float)(-w / 2.0);
      a.v[L * 12 + i * 4 + 1] = (float)(-h / 2.0);
      a.v[L * 12 + i * 4 + 2] = (float)(w / 2.0);
      a.v[L * 12 + i * 4 + 3] = (float)(h / 2.0);
    }
}

extern "C" void kernel_launch(void* const* d_in, const int* in_sizes, int n_in,
                              void* d_out, int out_size, void* d_ws, size_t ws_size,
                              hipStream_t stream) {
  (void)out_size; (void)ws_size;
  const float *p2=0,*p3=0,*p4=0,*p5=0,*wconv=0,*bconv=0,*wobj=0,*bobj=0,*wdel=0,*bdel=0;
  for (int i = 0; i < n_in; ++i) {
    switch (in_sizes[i]) {
      case 31719424: p2 = (const float*)d_in[i]; break;
      case 7929856:  p3 = (const float*)d_in[i]; break;
      case 1982464:  p4 = (const float*)d_in[i]; break;
      case 495616:   p5 = (const float*)d_in[i]; break;
      case 589824:   wconv = (const float*)d_in[i]; break;
      case 256:      bconv = (const float*)d_in[i]; break;
      case 768:      wobj = (const float*)d_in[i]; break;
      case 3:        bobj = (const float*)d_in[i]; break;
      case 3072:     wdel = (const float*)d_in[i]; break;
      case 12:       bdel = (const float*)d_in[i]; break;
      default: break;
    }
  }
  float* out = (float*)d_out;

  char* ws = (char*)d_ws;
  size_t off = 0;
  auto A = [&](size_t n) -> char* {
    char* p = ws + off;
    off = (off + n + 255) & ~(size_t)255;
    return p;
  };
  float* logits  = (float*)A(2ull * NC_TOT * 4);
  u8* validB     = (u8*)A(2ull * NC_TOT);
  float* boxes   = (float*)A(2ull * NC_TOT * 16);
  float* wt      = (float*)A(589824ull * 4);
  u64* Ksel      = (u64*)A(8ull * 262144 * 8);
  u64* Knms      = (u64*)A(2ull * 8192 * 8);
  u32* sel_cand  = (u32*)A(2ull * 8000 * 4);

  Anc48 anc; make_anc48(anc);

  wtr_k<<<(589824 + 255) / 256, 256, 0, stream>>>(wconv, wt);

  conv_f32<176, 352, 4><<<dim3(44 * 44, 2), 256, 0, stream>>>(
      p2, wt, bconv, wobj, bobj, wdel, bdel, logits, validB, boxes, 0, anc, 44);
  conv_f32<88, 176, 8><<<dim3(22 * 22, 2), 256, 0, stream>>>(
      p3, wt, bconv, wobj, bobj, wdel, bdel, logits, validB, boxes, 1, anc, 22);
  conv_f32<44, 88, 16><<<dim3(11 * 11, 2), 256, 0, stream>>>(
      p4, wt, bconv, wobj, bobj, wdel, bdel, logits, validB, boxes, 2, anc, 11);
  conv_f32<22, 44, 32><<<dim3(6 * 6, 2), 256, 0, stream>>>(
      p5, wt, bconv, wobj, bobj, wdel, bdel, logits, validB, boxes, 3, anc, 6);

  fill_sel<<<(8 * 262144) / 256, 256, 0, stream>>>(logits, Ksel);
  for (int k = 2; k <= 262144; k <<= 1)
    for (int j = k >> 1; j > 0; j >>= 1)
      bpass1<<<(8 * 262144) / 256, 256, 0, stream>>>(Ksel, k, j,
                                                     8 * 262144, 262143);

  fill_nms<<<(2 * 8192) / 256, 256, 0, stream>>>(Ksel, logits, validB,
                                                 Knms, sel_cand);
  sortnms_k<<<2, 512, 0, stream>>>(Knms);

  nms_f32_k<<<2, 64, 0, stream>>>(Knms, sel_cand, logits, validB, boxes, out);
}

// Round 18
// 6814.131 us; speedup vs baseline: 1.3208x; 1.3208x over previous
//
#include <hip/hip_runtime.h>
#include <math.h>

// ---------------------------------------------------------------------------
// RPN forward — round 18: R17 bit-exact arithmetic (numpy einsum semantics),
// optimized: chunked-LDS conv (4 blocks/CU), radix select (R5-validated),
// bitmask+scan NMS (R4-validated). Decision arithmetic unchanged.
// ---------------------------------------------------------------------------

#define NC_TOT 246840
typedef unsigned long long u64;
typedef unsigned int u32;
typedef unsigned char u8;

struct Anc48 { float v[48]; };
struct SelSt { unsigned int prefix; int need; };

__device__ __forceinline__ u32 sortable32(float f) {
  u32 u = __float_as_uint(f);
  return (u & 0x80000000u) ? ~u : (u | 0x80000000u);
}
__device__ __forceinline__ int lvl_base_of(int lvl) {
  return (lvl == 0) ? 0 : (lvl == 1) ? 185856 : (lvl == 2) ? 232320 : 243936;
}
__device__ __forceinline__ int lvl_N_of(int lvl) {
  return (lvl == 0) ? 185856 : (lvl == 1) ? 46464 : (lvl == 2) ? 11616 : 2904;
}
__device__ __forceinline__ u64 make_key(float sc, int lvl, int jrel) {
  return ((u64)(~sortable32(sc)) << 32) | (u32)((lvl << 18) | jrel);
}

// ---------------------------------------------------------------------------
// weight transpose: wt[(ci*9+tap)*256 + co] = wconv[co][ci][tap]
// ---------------------------------------------------------------------------
__global__ __launch_bounds__(256)
void wtr_k(const float* __restrict__ wconv, float* __restrict__ wt) {
  int g = blockIdx.x * 256 + threadIdx.x;
  if (g >= 589824) return;
  wt[g] = wconv[(size_t)(g & 255) * 2304 + (g >> 8)];
}

// ---------------------------------------------------------------------------
// conv+heads+decode, f32, NO fused multiply-add (numpy semantics), k-order
// (ci outer asc, tap inner asc). LDS x-staging chunked 4x64 ci -> 34.7KB LDS.
// Block=256, tile 8(w)x4(h); thread=(cog 0..31, slot 0..7).
// ---------------------------------------------------------------------------
template<int H, int W, int STRIDE>
__global__ __launch_bounds__(256)
void conv_f32(const float* __restrict__ x, const float* __restrict__ wt,
              const float* __restrict__ bconv, const float* __restrict__ wobj,
              const float* __restrict__ bobj, const float* __restrict__ wdel,
              const float* __restrict__ bdel,
              float* __restrict__ logitsB, u8* __restrict__ validB,
              float* __restrict__ boxesB, int lvl, Anc48 anc, int tiles_x)
{
#pragma clang fp contract(off)
  __shared__ __align__(16) char smem[34688];
  float* xs = (float*)smem;                 // chunk: [64][6][10]
  const int tid = threadIdx.x;
  const int img = blockIdx.y;
  const int ty = blockIdx.x / tiles_x, tx = blockIdx.x - ty * tiles_x;
  const int y0 = ty * 4, x0 = tx * 8;
  const int base = lvl_base_of(lvl);
  const float* xin = x + (size_t)img * 256 * H * W;

  const int cog = tid >> 3, slot = tid & 7;
  const int row = slot >> 1, half = slot & 1;
  float acc[8][4];
#pragma unroll
  for (int c = 0; c < 8; ++c)
#pragma unroll
    for (int j = 0; j < 4; ++j) acc[c][j] = 0.f;

  for (int cc = 0; cc < 4; ++cc) {
    __syncthreads();   // previous chunk fully consumed
    for (int idx = tid; idx < 64 * 60; idx += 256) {
      int cil = idx / 60; int rem = idx - cil * 60;
      int r = rem / 10; int c = rem - r * 10;
      int gy = y0 - 1 + r, gx = x0 - 1 + c;
      float v = 0.f;
      if (gy >= 0 && gy < H && gx >= 0 && gx < W)
        v = xin[(size_t)(cc * 64 + cil) * H * W + (size_t)gy * W + gx];
      xs[idx] = v;
    }
    __syncthreads();

    for (int cil = 0; cil < 64; ++cil) {
      const int ci = cc * 64 + cil;
      float xr[3][6];
#pragma unroll
      for (int dr = 0; dr < 3; ++dr) {
        const float* rp = &xs[cil * 60 + (row + dr) * 10 + half * 4];
        float2 av = *(const float2*)(rp);
        float2 bv = *(const float2*)(rp + 2);
        float2 cv = *(const float2*)(rp + 4);
        xr[dr][0] = av.x; xr[dr][1] = av.y; xr[dr][2] = bv.x;
        xr[dr][3] = bv.y; xr[dr][4] = cv.x; xr[dr][5] = cv.y;
      }
#pragma unroll
      for (int tap = 0; tap < 9; ++tap) {
        const int ky = tap / 3, kx = tap - ky * 3;
        const float4* wp = (const float4*)(wt + (((size_t)(ci * 9 + tap)) << 8)
                                           + (cog << 3));
        float4 wA = wp[0], wB = wp[1];
        float wv[8] = {wA.x, wA.y, wA.z, wA.w, wB.x, wB.y, wB.z, wB.w};
#pragma unroll
        for (int c = 0; c < 8; ++c) {
          // separate mul and add, each rounded (no contraction)
          acc[c][0] = acc[c][0] + (xr[ky][kx + 0] * wv[c]);
          acc[c][1] = acc[c][1] + (xr[ky][kx + 1] * wv[c]);
          acc[c][2] = acc[c][2] + (xr[ky][kx + 2] * wv[c]);
          acc[c][3] = acc[c][3] + (xr[ky][kx + 3] * wv[c]);
        }
      }
    }
  }
  __syncthreads();                 // all xs reads done; smem reused as tl

  // bias + relu -> tl[256 co][32 px]
  float* tl = (float*)smem;
  {
#pragma unroll
    for (int c = 0; c < 8; ++c) {
      float bv = bconv[cog * 8 + c];
#pragma unroll
      for (int j = 0; j < 4; ++j) {
        float v = acc[c][j] + bv;
        v = fmaxf(v, 0.f);
        tl[(cog * 8 + c) * 32 + row * 8 + half * 4 + j] = v;
      }
    }
  }
  __syncthreads();

  // heads: per pixel, 15 dots, sequential separate mul+add over co 0..255
  float* hd = (float*)(smem + 32768);   // [15][32]
  if (tid < 32) {
    int p = tid;
    for (int ch = 0; ch < 15; ++ch) {
      const float* wh = (ch < 3) ? (wobj + (size_t)ch * 256)
                                 : (wdel + (size_t)(ch - 3) * 256);
      float s = 0.f;
      for (int co = 0; co < 256; ++co) s = s + (tl[co * 32 + p] * wh[co]);
      hd[ch * 32 + p] = s;
    }
  }
  __syncthreads();

  // decode: strict f32 separate ops, CR exp
  if (tid < 96) {
    int p = tid / 3, a = tid - p * 3;
    int X = x0 + (p & 7), Y = y0 + (p >> 3);
    if (X < W && Y < H) {
      float sx = (float)(X * STRIDE), sy = (float)(Y * STRIDE);
      const float* av = &anc.v[lvl * 12 + a * 4];
      size_t cbase = (size_t)img * NC_TOT + (size_t)base + (size_t)(Y * W + X) * 3;
      float lg = hd[a * 32 + p] + bobj[a];
      float dx = hd[(3 + a * 4 + 0) * 32 + p] + bdel[a * 4 + 0];
      float dy = hd[(3 + a * 4 + 1) * 32 + p] + bdel[a * 4 + 1];
      float dw = hd[(3 + a * 4 + 2) * 32 + p] + bdel[a * 4 + 2];
      float dh = hd[(3 + a * 4 + 3) * 32 + p] + bdel[a * 4 + 3];
      float x1a = sx + av[0], y1a = sy + av[1];
      float x2a = sx + av[2], y2a = sy + av[3];
      float wa = x2a - x1a, ha = y2a - y1a;
      float cxa = x1a + 0.5f * wa, cya = y1a + 0.5f * ha;
      float dwc = fminf(dw, (float)4.135166556742356);
      float dhc = fminf(dh, (float)4.135166556742356);
      float pcx = (dx * wa) + cxa, pcy = (dy * ha) + cya;
      float ew = (float)exp((double)dwc);   // correctly-rounded f32 exp
      float eh = (float)exp((double)dhc);
      float pw = ew * wa, ph = eh * ha;
      float bx1 = pcx - (0.5f * pw), by1 = pcy - (0.5f * ph);
      float bx2 = pcx + (0.5f * pw), by2 = pcy + (0.5f * ph);
      bx1 = fminf(fmaxf(bx1, 0.f), 1408.f);
      bx2 = fminf(fmaxf(bx2, 0.f), 1408.f);
      by1 = fminf(fmaxf(by1, 0.f), 704.f);
      by2 = fminf(fmaxf(by2, 0.f), 704.f);
      bool vld = (bx2 - bx1 > 0.f) && (by2 - by1 > 0.f);
      logitsB[cbase + a] = lg;
      validB[cbase + a] = vld ? 1 : 0;
      *(float4*)(boxesB + (cbase + a) * 4) = make_float4(bx1, by1, bx2, by2);
    }
  }
}

// ---------------------------------------------------------------------------
// 4-pass radix select of top-2000 per (img,lvl) on sortable32(logit).
// Validated: R5(radix) == R7(full sort) bit-identical.
// ---------------------------------------------------------------------------
__global__ void init_k(SelSt* st, int* cntgt, int* tiecnt) {
  int t = threadIdx.x;
  if (t < 8) { st[t].prefix = 0u; st[t].need = 2000; cntgt[t] = 0; tiecnt[t] = 0; }
}

__global__ __launch_bounds__(256)
void hist_k(const float* __restrict__ logits, const SelSt* __restrict__ st,
            unsigned int* __restrict__ hist, int pass) {
  __shared__ unsigned int h[256][17];
  const int tid = threadIdx.x;
  const int seg = blockIdx.x; const int img = seg >> 2, lvl = seg & 3;
  for (int i = tid; i < 256 * 17; i += 256) ((unsigned int*)h)[i] = 0u;
  __syncthreads();
  const int N = lvl_N_of(lvl);
  const int base = lvl_base_of(lvl);
  const unsigned int prefix = st[seg].prefix;
  const int shift = 24 - 8 * pass;
  const float* src = logits + (size_t)img * NC_TOT + base;
  const int sub = tid & 15;
  for (int i = tid; i < N; i += 256) {
    u32 u = sortable32(src[i]);
    bool ok = true;
    if (pass) ok = ((u >> (shift + 8)) == prefix);
    if (ok) atomicAdd(&h[(u >> shift) & 255][sub], 1u);
  }
  __syncthreads();
  for (int b = tid; b < 256; b += 256) {
    unsigned int s = 0;
    for (int k = 0; k < 16; ++k) s += h[b][k];
    hist[seg * 256 + b] = s;
  }
}

__global__ void select_k(const unsigned int* __restrict__ hist, SelSt* st) {
  int t = threadIdx.x;
  if (t >= 8) return;
  int need = st[t].need;
  unsigned int cum = 0; int chosen = 0;
  for (int b = 255; b >= 0; --b) {
    unsigned int c = hist[t * 256 + b];
    if (cum + c >= (unsigned int)need) { chosen = b; break; }
    cum += c;
  }
  st[t].prefix = (st[t].prefix << 8) | (unsigned int)chosen;
  st[t].need = need - (int)cum;
}

__global__ __launch_bounds__(256)
void compact_k(const float* __restrict__ logits, const u8* __restrict__ validB,
               const SelSt* __restrict__ st,
               int* cntgt, int* tiecnt, int* tiebuf,
               u64* __restrict__ sel_key) {
  int gi = blockIdx.x * 256 + threadIdx.x;
  if (gi >= 2 * NC_TOT) return;
  int img = gi / NC_TOT; int j = gi - img * NC_TOT;
  int lvl = (j < 185856) ? 0 : (j < 232320) ? 1 : (j < 243936) ? 2 : 3;
  int base = lvl_base_of(lvl);
  int seg = img * 4 + lvl;
  size_t ci = (size_t)img * NC_TOT + j;
  u32 u = sortable32(logits[ci]);
  u32 T = st[seg].prefix;
  if (u > T) {
    int slot = atomicAdd(&cntgt[seg], 1);
    float sc = validB[ci] ? logits[ci] : -1e9f;
    sel_key[img * 8000 + lvl * 2000 + slot] = make_key(sc, lvl, j - base);
  } else if (u == T) {
    int p = atomicAdd(&tiecnt[seg], 1);
    if (p < 1024) tiebuf[seg * 1024 + p] = j;
  }
}

// ties share one exact f32 logit value -> top_k takes lowest indices first
__global__ __launch_bounds__(256)
void tie_k(const float* __restrict__ logits, const u8* __restrict__ validB,
           const SelSt* __restrict__ st, const int* cntgt, const int* tiecnt,
           const int* tiebuf, u64* __restrict__ sel_key) {
  int seg = blockIdx.x; int img = seg >> 2, lvl = seg & 3;
  int base = lvl_base_of(lvl);
  int n = tiecnt[seg]; if (n > 1024) n = 1024;
  int ne = st[seg].need; int bslot = cntgt[seg];
  for (int t = threadIdx.x; t < n; t += 256) {
    int my = tiebuf[seg * 1024 + t];
    int rank = 0;
    for (int k = 0; k < n; ++k) rank += (tiebuf[seg * 1024 + k] < my) ? 1 : 0;
    if (rank < ne) {
      size_t ci = (size_t)img * NC_TOT + my;
      float sc = validB[ci] ? logits[ci] : -1e9f;
      sel_key[img * 8000 + lvl * 2000 + bslot + rank] = make_key(sc, lvl, my - base);
    }
  }
}

// ---------------------------------------------------------------------------
// NMS order: bitonic sort 8192 keys (score desc, lvl asc, idx asc)
// ---------------------------------------------------------------------------
__global__ __launch_bounds__(512)
void sortnms_k(const u64* __restrict__ sel_key, u64* __restrict__ K) {
  __shared__ u64 key[8192];
  const int tid = threadIdx.x; const int img = blockIdx.x;
  for (int i = tid; i < 8192; i += 512)
    key[i] = (i < 8000) ? sel_key[img * 8000 + i] : ~0ull;
  __syncthreads();
  for (int kk = 2; kk <= 8192; kk <<= 1) {
    for (int j = kk >> 1; j > 0; j >>= 1) {
      for (int i = tid; i < 8192; i += 512) {
        int ij = i ^ j;
        if (ij > i) {
          bool up = ((i & kk) == 0);
          u64 a = key[i], b = key[ij];
          if ((a > b) == up) { key[i] = b; key[ij] = a; }
        }
      }
      __syncthreads();
    }
  }
  for (int i = tid; i < 8192; i += 512) K[img * 8192 + i] = key[i];
}

// ---------------------------------------------------------------------------
// gather sorted candidates: offset boxes (for IoU), output rows, validw
// ---------------------------------------------------------------------------
__global__ __launch_bounds__(512)
void gather_k(const u64* __restrict__ Knms,
              const float* __restrict__ logits, const u8* __restrict__ validB,
              const float* __restrict__ boxes,
              float* __restrict__ bo_sorted, float* __restrict__ bc_sorted,
              float* __restrict__ sc_sorted, u64* __restrict__ validw) {
#pragma clang fp contract(off)
  const int img = blockIdx.x; const int tid = threadIdx.x;
  const int lane = tid & 63, wv = tid >> 6;       // 8 waves
  for (int w = wv; w < 125; w += 8) {
    int i = w * 64 + lane;
    u64 k = Knms[img * 8192 + i];
    u32 low = (u32)(k & 0xFFFFFull);
    int lvl = low >> 18; int jr = low & 0x3FFFF;
    size_t ci = (size_t)img * NC_TOT + lvl_base_of(lvl) + jr;
    float sc = validB[ci] ? logits[ci] : -1e9f;
    const float4 b = *(const float4*)(boxes + ci * 4);
    float off = (float)lvl * 4096.0f;
    sc_sorted[img * 8192 + i] = sc;
    *(float4*)(bc_sorted + (size_t)(img * 8192 + i) * 4) = b;
    *(float4*)(bo_sorted + (size_t)(img * 8192 + i) * 4) =
        make_float4(b.x + off, b.y + off, b.z + off, b.w + off);
    u64 blt = __ballot(sc > -1e8f);
    if (lane == 0) validw[img * 125 + w] = blt;
  }
}

// ---------------------------------------------------------------------------
// IoU bitmask, f32, same op semantics as the validated kept-list NMS
// ---------------------------------------------------------------------------
__global__ __launch_bounds__(256)
void mask_k(const float* __restrict__ bo_sorted, u64* __restrict__ mask) {
#pragma clang fp contract(off)
  const int img = blockIdx.z; const int rblk = blockIdx.y, cblk = blockIdx.x;
  __shared__ float4 cb[64];
  const int tid = threadIdx.x;
  if (tid < 64)
    cb[tid] = *(const float4*)(bo_sorted + (size_t)(img * 8192 + cblk * 64 + tid) * 4);
  __syncthreads();
  const int wv = tid >> 6, lane = tid & 63;
  float4 my = cb[lane];
  float areaB = (my.z - my.x) * (my.w - my.y);
  for (int rr = 0; rr < 16; ++rr) {
    int rowi = rblk * 64 + wv * 16 + rr;
    float4 rb = *(const float4*)(bo_sorted + (size_t)(img * 8192 + rowi) * 4);
    float areaA = (rb.z - rb.x) * (rb.w - rb.y);
    float ltx = fmaxf(rb.x, my.x), lty = fmaxf(rb.y, my.y);
    float rbx = fminf(rb.z, my.z), rby = fminf(rb.w, my.w);
    float w = fmaxf(rbx - ltx, 0.f), h = fmaxf(rby - lty, 0.f);
    float inter = w * h;
    float uni = (areaA + areaB) - inter;
    bool s = (uni > 0.f) && ((inter / uni) > 0.7f);
    u64 m = __ballot(s);
    if (lane == 0) mask[((size_t)img * 8000 + rowi) * 125 + cblk] = m;
  }
}

// ---------------------------------------------------------------------------
// sequential greedy suppression scan (validated: R4(mask+scan) == R5(kept))
// ---------------------------------------------------------------------------
__global__ void scan_k(const u64* __restrict__ mask, const u64* __restrict__ validw,
                       int* __restrict__ kept, int* __restrict__ kept_count) {
  const int img = blockIdx.x; const int lane = threadIdx.x;  // 64 threads
  u64 acc0 = ~validw[img * 125 + lane];
  u64 acc1 = (lane < 61) ? ~validw[img * 125 + 64 + lane] : ~0ull;
  int count = 0;
  for (int c = 0; c < 125 && count < 1000; ++c) {
    u64 cur = (c < 64) ? __shfl(acc0, c) : __shfl(acc1, c - 64);
    while (true) {
      u64 free_ = ~cur;
      if (free_ == 0ull) break;
      int b = __builtin_ctzll(free_);
      int i = c * 64 + b;
      const u64* rowp = mask + ((size_t)img * 8000 + i) * 125;
      u64 w0 = rowp[lane];
      u64 w1 = (lane < 61) ? rowp[64 + lane] : 0ull;
      acc0 |= w0; acc1 |= w1;
      u64 diag = (c < 64) ? __shfl(w0, c) : __shfl(w1, c - 64);
      cur |= diag;
      cur |= (1ull << b);
      if (lane == 0) kept[img * 1000 + count] = i;
      ++count;
      if (count >= 1000) break;
    }
  }
  if (lane == 0) kept_count[img] = count;
}

__global__ void out_k(const int* __restrict__ kept, const int* __restrict__ kept_count,
                      const float* __restrict__ sc_sorted, const float* __restrict__ bc_sorted,
                      float* __restrict__ out) {
  const int img = blockIdx.x; const int kc = kept_count[img];
  for (int j = threadIdx.x; j < 1000; j += 256) {
    float x1 = 0.f, y1 = 0.f, x2 = 0.f, y2 = 0.f, sc = -1e9f;
    if (j < kc) {
      int i = kept[img * 1000 + j];
      float4 b = *(const float4*)(bc_sorted + (size_t)(img * 8192 + i) * 4);
      x1 = b.x; y1 = b.y; x2 = b.z; y2 = b.w;
      sc = sc_sorted[img * 8192 + i];
    }
    float* o = out + ((size_t)img * 1000 + j) * 5;
    o[0] = x1; o[1] = y1; o[2] = x2; o[3] = y2; o[4] = sc;
  }
}

// ---------------------------------------------------------------------------
static void make_anc48(Anc48& a) {
  const double sizes[4] = {32.0, 64.0, 128.0, 256.0};
  const double ratios[3] = {0.5, 1.0, 2.0};
  for (int L = 0; L < 4; ++L)
    for (int i = 0; i < 3; ++i) {
      double w = sizes[L] * sqrt(1.0 / ratios[i]);
      double h = sizes[L] * sqrt(ratios[i]);
      a.v[L * 12 + i * 4 + 0] = (float)(-w / 2.0);
      a.v[L * 12 + i * 4 + 1] = (float)(-h / 2.0);
      a.v[L * 12 + i * 4 + 2] = (float)(w / 2.0);
      a.v[L * 12 + i * 4 + 3] = (float)(h / 2.0);
    }
}

extern "C" void kernel_launch(void* const* d_in, const int* in_sizes, int n_in,
                              void* d_out, int out_size, void* d_ws, size_t ws_size,
                              hipStream_t stream) {
  (void)out_size; (void)ws_size;
  const float *p2=0,*p3=0,*p4=0,*p5=0,*wconv=0,*bconv=0,*wobj=0,*bobj=0,*wdel=0,*bdel=0;
  for (int i = 0; i < n_in; ++i) {
    switch (in_sizes[i]) {
      case 31719424: p2 = (const float*)d_in[i]; break;
      case 7929856:  p3 = (const float*)d_in[i]; break;
      case 1982464:  p4 = (const float*)d_in[i]; break;
      case 495616:   p5 = (const float*)d_in[i]; break;
      case 589824:   wconv = (const float*)d_in[i]; break;
      case 256:      bconv = (const float*)d_in[i]; break;
      case 768:      wobj = (const float*)d_in[i]; break;
      case 3:        bobj = (const float*)d_in[i]; break;
      case 3072:     wdel = (const float*)d_in[i]; break;
      case 12:       bdel = (const float*)d_in[i]; break;
      default: break;
    }
  }
  float* out = (float*)d_out;

  char* ws = (char*)d_ws;
  size_t off = 0;
  auto A = [&](size_t n) -> char* {
    char* p = ws + off;
    off = (off + n + 255) & ~(size_t)255;
    return p;
  };
  float* logits   = (float*)A(2ull * NC_TOT * 4);
  u8* validB      = (u8*)A(2ull * NC_TOT);
  float* boxes    = (float*)A(2ull * NC_TOT * 16);
  float* wt       = (float*)A(589824ull * 4);
  u64* sel_key    = (u64*)A(2ull * 8000 * 8);
  u64* Knms       = (u64*)A(2ull * 8192 * 8);
  float* bo_sorted = (float*)A(2ull * 8192 * 16);
  float* bc_sorted = (float*)A(2ull * 8192 * 16);
  float* sc_sorted = (float*)A(2ull * 8192 * 4);
  u64* validw     = (u64*)A(2ull * 125 * 8);
  u64* maskb      = (u64*)A(2ull * 8000 * 125 * 8);
  int* kept       = (int*)A(2000 * 4);
  int* kept_count = (int*)A(64);
  unsigned int* hist = (unsigned int*)A(8 * 256 * 4);
  SelSt* st       = (SelSt*)A(8 * sizeof(SelSt));
  int* cntgt      = (int*)A(64);
  int* tiecnt     = (int*)A(64);
  int* tiebuf     = (int*)A(8 * 1024 * 4);

  Anc48 anc; make_anc48(anc);

  wtr_k<<<(589824 + 255) / 256, 256, 0, stream>>>(wconv, wt);

  conv_f32<176, 352, 4><<<dim3(44 * 44, 2), 256, 0, stream>>>(
      p2, wt, bconv, wobj, bobj, wdel, bdel, logits, validB, boxes, 0, anc, 44);
  conv_f32<88, 176, 8><<<dim3(22 * 22, 2), 256, 0, stream>>>(
      p3, wt, bconv, wobj, bobj, wdel, bdel, logits, validB, boxes, 1, anc, 22);
  conv_f32<44, 88, 16><<<dim3(11 * 11, 2), 256, 0, stream>>>(
      p4, wt, bconv, wobj, bobj, wdel, bdel, logits, validB, boxes, 2, anc, 11);
  conv_f32<22, 44, 32><<<dim3(6 * 6, 2), 256, 0, stream>>>(
      p5, wt, bconv, wobj, bobj, wdel, bdel, logits, validB, boxes, 3, anc, 6);

  init_k<<<1, 64, 0, stream>>>(st, cntgt, tiecnt);
  for (int pass = 0; pass < 4; ++pass) {
    hist_k<<<8, 256, 0, stream>>>(logits, st, hist, pass);
    select_k<<<1, 64, 0, stream>>>(hist, st);
  }
  compact_k<<<(2 * NC_TOT + 255) / 256, 256, 0, stream>>>(
      logits, validB, st, cntgt, tiecnt, tiebuf, sel_key);
  tie_k<<<8, 256, 0, stream>>>(logits, validB, st, cntgt, tiecnt, tiebuf, sel_key);

  sortnms_k<<<2, 512, 0, stream>>>(sel_key, Knms);
  gather_k<<<2, 512, 0, stream>>>(Knms, logits, validB, boxes,
                                  bo_sorted, bc_sorted, sc_sorted, validw);
  mask_k<<<dim3(125, 125, 2), 256, 0, stream>>>(bo_sorted, maskb);
  scan_k<<<2, 64, 0, stream>>>(maskb, validw, kept, kept_count);
  out_k<<<2, 256, 0, stream>>>(kept, kept_count, sc_sorted, bc_sorted, out);
}